// Round 6
// baseline (483.151 us; speedup 1.0000x reference)
//
#include <hip/hip_runtime.h>
#include <hip/hip_cooperative_groups.h>
#include <hip/hip_bf16.h>
#include <math.h>

namespace cg = cooperative_groups;

// Self_Attention_Local R6: single cooperative kernel (3 phases + 2 grid.sync)
//   P1: Wq/Wk/Wv -> Wp[x][h][i][k] bf16; Wout -> Wout_t[col][h*128+i] bf16
//   P2: per (patch-group, head) block: QKV MFMA, two-pass instance-norm stats,
//       folded softmax exp2((S-mu)*rs), PV with ones-row row-sums, ctx -> ws
//       bf16 [out_row][h*128+i]. Conflict-free 16B-chunk swizzles for P/V/ctx.
//   P3: out (4096x128) = ctx2 (4096x1024) @ WoutB (1024x128) bf16 MFMA.
// Fallback: same phases as 3 separate kernels if cooperative launch fails.

typedef short bfrag __attribute__((ext_vector_type(8)));   // 8 bf16 = 4 VGPRs
typedef float f32x4 __attribute__((ext_vector_type(4)));

static __device__ __forceinline__ short f2bf(float x) {
    unsigned u = __builtin_bit_cast(unsigned, x);
    return (short)((u + 0x8000u) >> 16);       // round-half-up, 2 VALU ops
}
static __device__ __forceinline__ bfrag bzero() {
    bfrag z;
    #pragma unroll
    for (int j = 0; j < 8; ++j) z[j] = 0;
    return z;
}

// LDS zones (shorts): QT 0..4095 | KT 4096..8191 | VS 8192..12287 (ctx overlay)
//                     PS 12288..20479 (4 waves x 16 x 128)
#define QT 0
#define KT 4096
#define VS 8192
#define PS 12288

// ---------------- phase 1: weight converts (blocks 0..127) ----------------
__device__ __forceinline__ void conv_phase(
    const float* __restrict__ Wq, const float* __restrict__ Wk,
    const float* __restrict__ Wv, const float* __restrict__ Wout,
    short* __restrict__ Wp, short* __restrict__ Wout_t,
    short* lds, int bid, int t)
{
    if (bid < 96) {
        short* lt = lds;                       // 32 x 129
        const int x = bid >> 5, h = (bid >> 2) & 7, k0 = (bid & 3) * 32;
        const float* W = (x == 0) ? Wq : (x == 1) ? Wk : Wv;
        #pragma unroll 4
        for (int rr = 0; rr < 16; ++rr) {
            const int k = rr * 2 + (t >> 7);
            const int i = t & 127;
            lt[k * 129 + i] = f2bf(W[(k0 + k) * 1024 + i * 8 + h]);
        }
        __syncthreads();
        short* dst = Wp + (x * 8 + h) * 16384;
        #pragma unroll
        for (int pp = 0; pp < 4; ++pp) {
            const int i  = pp * 32 + (t >> 3);
            const int kk = (t & 7) * 4;
            short4 v;
            v.x = lt[(kk + 0) * 129 + i]; v.y = lt[(kk + 1) * 129 + i];
            v.z = lt[(kk + 2) * 129 + i]; v.w = lt[(kk + 3) * 129 + i];
            *(short4*)&dst[i * 128 + k0 + kk] = v;
        }
    } else if (bid < 128) {
        short* lt = lds;                       // 128 x 33
        const int b2 = bid - 96;
        const int cq = b2 >> 3, rq = b2 & 7;
        #pragma unroll 4
        for (int ii = 0; ii < 16; ++ii) {
            const int rr = ii * 8 + (t >> 5);
            const int cc = t & 31;
            lt[rr * 33 + cc] = f2bf(Wout[(rq * 128 + rr) * 128 + cq * 32 + cc]);
        }
        __syncthreads();
        #pragma unroll
        for (int ii = 0; ii < 4; ++ii) {
            const int task = ii * 256 + t;
            const int cl = task >> 5, hh = (task >> 2) & 7, mg = task & 3;
            short4 v;
            v.x = lt[(hh + 8 * (mg * 4 + 0)) * 33 + cl];
            v.y = lt[(hh + 8 * (mg * 4 + 1)) * 33 + cl];
            v.z = lt[(hh + 8 * (mg * 4 + 2)) * 33 + cl];
            v.w = lt[(hh + 8 * (mg * 4 + 3)) * 33 + cl];
            *(short4*)&Wout_t[(cq * 32 + cl) * 1024 + hh * 128 + rq * 16 + mg * 4] = v;
        }
    }
}

// ---------------- phase 2: fused attention ----------------
__device__ __forceinline__ void attn_phase(
    const float* __restrict__ emb,      // [4096][128] fp32
    const short* __restrict__ Wp,       // [3][8][128 i][128 k]
    short* __restrict__ ctx2,           // [4096 out-rows][h*128+i] bf16
    short* lds, int bid, int t)
{
    const int pg = bid >> 3, h = bid & 7;
    const int w = t >> 6, lane = t & 63;
    const int m16 = lane & 15, quad = lane >> 4, q8 = quad * 8;

    // ===== QKV: (32x128) @ W_h (128x128) x3, 16x16x32 =====
    {
        bfrag a[2][4];
        #pragma unroll
        for (int tm = 0; tm < 2; ++tm)
            #pragma unroll
            for (int ks = 0; ks < 4; ++ks) {
                const float* er = emb + (size_t)(pg*32 + tm*16 + m16) * 128 + ks*32 + q8;
                const float4 x0 = *(const float4*)er;
                const float4 x1 = *(const float4*)(er + 4);
                bfrag f;
                f[0]=f2bf(x0.x); f[1]=f2bf(x0.y); f[2]=f2bf(x0.z); f[3]=f2bf(x0.w);
                f[4]=f2bf(x1.x); f[5]=f2bf(x1.y); f[6]=f2bf(x1.z); f[7]=f2bf(x1.w);
                a[tm][ks] = f;
            }
        #pragma unroll
        for (int tt = 0; tt < 6; ++tt) {
            const int nt = w * 6 + tt;            // 0..23 = {q,k,v} x 8 i-tiles
            const int x  = nt >> 3;
            const int i0 = (nt & 7) * 16;
            const short* Wb = Wp + ((x*8 + h)*128 + i0 + m16) * 128;
            bfrag bb[4];
            #pragma unroll
            for (int ks = 0; ks < 4; ++ks)
                bb[ks] = *(const bfrag*)&Wb[ks*32 + q8];
            f32x4 c0 = {0.f,0.f,0.f,0.f}, c1 = {0.f,0.f,0.f,0.f};
            #pragma unroll
            for (int ks = 0; ks < 4; ++ks) {
                c0 = __builtin_amdgcn_mfma_f32_16x16x32_bf16(a[0][ks], bb[ks], c0, 0,0,0);
                c1 = __builtin_amdgcn_mfma_f32_16x16x32_bf16(a[1][ks], bb[ks], c1, 0,0,0);
            }
            #pragma unroll
            for (int tm = 0; tm < 2; ++tm) {
                const f32x4 cc = tm ? c1 : c0;
                const int mrow0 = tm*16 + quad*4;     // 4 consecutive tokens
                const int pl = mrow0 >> 3;
                const int p0 = mrow0 & 7;
                const int col = i0 + m16;
                if (x < 2) {                          // Qt/Kt transposed [i][p]
                    short4 v;
                    v.x = f2bf(cc[0]); v.y = f2bf(cc[1]);
                    v.z = f2bf(cc[2]); v.w = f2bf(cc[3]);
                    *(short4*)&lds[(x ? KT : QT) + pl*1024 + col*8 + p0] = v;
                } else {                              // V natural, chunk-swizzled
                    #pragma unroll
                    for (int r = 0; r < 4; ++r) {
                        const int p = p0 + r;
                        const int phys = ((col >> 3) + p + 2*pl) & 15;
                        lds[VS + pl*1024 + p*128 + phys*8 + (col & 7)] = f2bf(cc[r]);
                    }
                }
            }
        }
    }
    __syncthreads();

    // ===== hoist K^T and V fragments (wave w owns patch pl = w) =====
    bfrag bs[8], av[4];
    #pragma unroll
    for (int nt = 0; nt < 8; ++nt)
        bs[nt] = (quad == 0) ? *(const bfrag*)&lds[KT + w*1024 + (nt*16 + m16)*8] : bzero();
    #pragma unroll
    for (int ks = 0; ks < 4; ++ks) {
        if (m16 < 8) {
            const int phys = (4*ks + quad + m16 + 2*w) & 15;
            av[ks] = *(const bfrag*)&lds[VS + w*1024 + m16*128 + phys*8];
        } else if (m16 == 8) {                 // ones row -> C[8][i] = rowsum_i
            bfrag o;
            #pragma unroll
            for (int j = 0; j < 8; ++j) o[j] = (short)0x3F80;
            av[ks] = o;
        } else
            av[ks] = bzero();
    }

    // ===== pass 1: instance-norm stats (full 128x128, biased var) =====
    float rs2, nbias;
    {
        float ls = 0.f, lq = 0.f;
        #pragma unroll 1
        for (int mb = 0; mb < 8; ++mb) {
            const bfrag as = (quad == 0)
                ? *(const bfrag*)&lds[QT + w*1024 + (mb*16 + m16)*8] : bzero();
            #pragma unroll
            for (int nt = 0; nt < 8; ++nt) {
                f32x4 c = {0.f,0.f,0.f,0.f};
                c = __builtin_amdgcn_mfma_f32_16x16x32_bf16(as, bs[nt], c, 0,0,0);
                #pragma unroll
                for (int r = 0; r < 4; ++r) { ls += c[r]; lq = fmaf(c[r], c[r], lq); }
            }
        }
        #pragma unroll
        for (int off = 1; off <= 32; off <<= 1) {
            ls += __shfl_xor(ls, off);
            lq += __shfl_xor(lq, off);
        }
        const float mean = ls * (1.f / 16384.f);
        const float var  = lq * (1.f / 16384.f) - mean * mean;
        rs2   = rsqrtf(var + 1e-5f) * 1.44269504f;
        nbias = -mean * rs2;
    }

    // ===== pass 2: 8 bands of 16 rows: scores -> exp -> P -> PV -> ctx =====
    short* ps = &lds[PS + w*2048];
    f32x4 c[8];
    {
        const bfrag as = (quad == 0) ? *(const bfrag*)&lds[QT + w*1024 + m16*8] : bzero();
        #pragma unroll
        for (int nt = 0; nt < 8; ++nt) {
            f32x4 z = {0.f,0.f,0.f,0.f};
            c[nt] = __builtin_amdgcn_mfma_f32_16x16x32_bf16(as, bs[nt], z, 0,0,0);
        }
    }
    #pragma unroll 1
    for (int mb = 0; mb < 8; ++mb) {
        // P store, conflict-free chunk swizzle: sigma(row)=2*(row>>2)+(row&1)
        #pragma unroll
        for (int nt = 0; nt < 8; ++nt)
            #pragma unroll
            for (int r = 0; r < 4; ++r) {
                const int row = quad*4 + r;
                const int phys = ((2*nt + (m16 >> 3)) + 2*(row >> 2) + (row & 1)) & 15;
                ps[row*128 + phys*8 + (m16 & 7)] =
                    f2bf(exp2f(fmaf(c[nt][r], rs2, nbias)));
            }
        // next band's scores issue between P-write and PV-read
        if (mb < 7) {
            const bfrag as = (quad == 0)
                ? *(const bfrag*)&lds[QT + w*1024 + ((mb+1)*16 + m16)*8] : bzero();
            #pragma unroll
            for (int nt = 0; nt < 8; ++nt) {
                f32x4 z = {0.f,0.f,0.f,0.f};
                c[nt] = __builtin_amdgcn_mfma_f32_16x16x32_bf16(as, bs[nt], z, 0,0,0);
            }
        }
        // PV: C[p][i16] = sum_j V[p][j] P[i][j]; B-frag = P row m16
        f32x4 cc = {0.f,0.f,0.f,0.f};
        #pragma unroll
        for (int ks = 0; ks < 4; ++ks) {
            const int phys = (4*ks + quad + 2*(m16 >> 2) + (m16 & 1)) & 15;
            const bfrag bp = *(const bfrag*)&ps[m16*128 + phys*8];
            cc = __builtin_amdgcn_mfma_f32_16x16x32_bf16(av[ks], bp, cc, 0,0,0);
        }
        const float s  = __shfl(cc[0], 32 + m16);   // C row 8 = row sums
        const float is = 1.0f / s;
        if (quad < 2) {
            #pragma unroll
            for (int r = 0; r < 4; ++r) {
                const int p = quad*4 + r;
                const int phys = ((2*mb + (m16 >> 3)) + p) & 15;
                lds[VS + w*1024 + p*128 + phys*8 + (m16 & 7)] = f2bf(cc[r] * is);
            }
        }
    }

    // ===== ctx -> global ctx2[out_row][h*128+i], coalesced 16B =====
    {
        const int pat = pg*4 + w;
        const int bb = pat >> 5, rem = pat & 31;
        const int dd = rem >> 4, hh = (rem >> 2) & 3, ww = rem & 3;
        #pragma unroll
        for (int it = 0; it < 2; ++it) {
            const int p = it*4 + quad;
            const int cch = m16;
            const int phys = (cch + p) & 15;
            const bfrag v = *(const bfrag*)&lds[VS + w*1024 + p*128 + phys*8];
            const int p1 = p >> 2, p2 = (p >> 1) & 1, p3 = p & 1;
            const int row = bb*256 + ((((dd*2 + p1)*4 + hh)*2 + p2)*4 + ww)*2 + p3;
            *(bfrag*)&ctx2[(size_t)row * 1024 + h*128 + cch*8] = v;
        }
    }
}

// ---------------- phase 3: out GEMM (blocks 0..255) ----------------
__device__ __forceinline__ void out_phase(
    const short* __restrict__ ctx2,    // [4096][1024]
    const short* __restrict__ Wout_t,  // [128 col][1024 k]
    float* __restrict__ out, int bid, int t)
{
    if (bid >= 256) return;
    const int w = t >> 6, lane = t & 63;
    const int m16 = lane & 15, quad = lane >> 4, q8 = quad * 8;
    const int row0 = bid * 16;

    f32x4 acc0 = {0.f,0.f,0.f,0.f}, acc1 = {0.f,0.f,0.f,0.f};
    const short* ar = ctx2   + (size_t)(row0 + m16) * 1024 + q8;
    const short* b0 = Wout_t + (size_t)((w*2 + 0)*16 + m16) * 1024 + q8;
    const short* b1 = Wout_t + (size_t)((w*2 + 1)*16 + m16) * 1024 + q8;
    #pragma unroll 4
    for (int ks = 0; ks < 32; ++ks) {
        const bfrag a   = *(const bfrag*)&ar[ks*32];
        const bfrag vb0 = *(const bfrag*)&b0[ks*32];
        const bfrag vb1 = *(const bfrag*)&b1[ks*32];
        acc0 = __builtin_amdgcn_mfma_f32_16x16x32_bf16(a, vb0, acc0, 0, 0, 0);
        acc1 = __builtin_amdgcn_mfma_f32_16x16x32_bf16(a, vb1, acc1, 0, 0, 0);
    }
    const int r0 = quad * 4;
    #pragma unroll
    for (int r = 0; r < 4; ++r) {
        out[(size_t)(row0 + r0 + r)*128 + (w*2 + 0)*16 + m16] = acc0[r];
        out[(size_t)(row0 + r0 + r)*128 + (w*2 + 1)*16 + m16] = acc1[r];
    }
}

// ---------------- cooperative mono-kernel ----------------
__global__ __launch_bounds__(256, 4) void mono(
    const float* __restrict__ emb, const float* __restrict__ Wq,
    const float* __restrict__ Wk,  const float* __restrict__ Wv,
    const float* __restrict__ Wout,
    short* __restrict__ Wp, short* __restrict__ Wout_t,
    short* __restrict__ ctx2, float* __restrict__ out)
{
    __shared__ short lds[20480];               // 40 KB
    const int bid = blockIdx.x, t = threadIdx.x;
    conv_phase(Wq, Wk, Wv, Wout, Wp, Wout_t, lds, bid, t);
    __threadfence();
    cg::this_grid().sync();
    attn_phase(emb, Wp, ctx2, lds, bid, t);
    __threadfence();
    cg::this_grid().sync();
    out_phase(ctx2, Wout_t, out, bid, t);
}

// ---------------- non-cooperative fallback ----------------
__global__ __launch_bounds__(256) void k_conv(
    const float* Wq, const float* Wk, const float* Wv, const float* Wout,
    short* Wp, short* Wout_t)
{
    __shared__ short lds[20480];
    conv_phase(Wq, Wk, Wv, Wout, Wp, Wout_t, lds, blockIdx.x, threadIdx.x);
}
__global__ __launch_bounds__(256, 4) void k_attn(
    const float* emb, const short* Wp, short* ctx2)
{
    __shared__ short lds[20480];
    attn_phase(emb, Wp, ctx2, lds, blockIdx.x, threadIdx.x);
}
__global__ __launch_bounds__(256) void k_out(
    const short* ctx2, const short* Wout_t, float* out)
{
    out_phase(ctx2, Wout_t, out, blockIdx.x, threadIdx.x);
}

extern "C" void kernel_launch(void* const* d_in, const int* in_sizes, int n_in,
                              void* d_out, int out_size, void* d_ws, size_t ws_size,
                              hipStream_t stream) {
    const float* emb  = (const float*)d_in[0];   // (512, 8, 128)
    const float* Wq   = (const float*)d_in[1];   // (128, 1024)
    const float* Wk   = (const float*)d_in[2];
    const float* Wv   = (const float*)d_in[3];
    const float* Wout = (const float*)d_in[4];   // (1024, 128)
    float* out = (float*)d_out;                  // 524288 floats

    short* ctx2   = (short*)d_ws;                // 4194304 shorts (8 MB)
    short* Wp     = ctx2 + 4194304;              // 393216
    short* Wout_t = Wp + 393216;                 // 131072   (total ~9 MB)

    void* args[] = { (void*)&emb, (void*)&Wq, (void*)&Wk, (void*)&Wv, (void*)&Wout,
                     (void*)&Wp, (void*)&Wout_t, (void*)&ctx2, (void*)&out };
    hipError_t err = hipLaunchCooperativeKernel((const void*)mono,
                                                dim3(1024), dim3(256),
                                                args, 0, stream);
    if (err != hipSuccess) {
        // same math, 3 launches
        k_conv<<<128, 256, 0, stream>>>(Wq, Wk, Wv, Wout, Wp, Wout_t);
        k_attn<<<1024, 256, 0, stream>>>(emb, Wp, ctx2);
        k_out<<<256, 256, 0, stream>>>(ctx2, Wout_t, out);
    }
}

// Round 7
// 128.061 us; speedup vs baseline: 3.7728x; 3.7728x over previous
//
#include <hip/hip_runtime.h>
#include <hip/hip_bf16.h>
#include <math.h>

// Self_Attention_Local R7: 3 kernels (coop grid.sync measured ~350us -> dead).
//   k_conv: weight permutes to bf16 (R6-verified).
//   k_attn: block=(4 patches, head), wave=1 patch. QKV MFMA -> Qt/Kt/Vs LDS.
//     Scores computed TRANSPOSED (S^T = K^T Q, 32x32x16, K=8 padded): C-layout
//     lane(l31,hi) reg r holds S^T[j=(r&3)+8(r>>2)+4hi+32mt][i=l31].
//     exp in regs; cross-lane repack (shfl_xor 32 + select) builds PV A-frags
//     A[i=l31][k=j] directly -> NO LDS round-trip for P. PV 32x32x16 with
//     V B-frags (n=p, ones row at p=8 gives row sums). Stats = 16-MFMA
//     recompute (mu folds into exp2 bias; no row max needed - scores are
//     instance-normalized). ctx -> LDS (swizzled, conflict-free) -> global
//     bf16 [out_row][h*128+i]. LDS 24 KB.
//   k_out: (4096x1024)@(1024x128) bf16 MFMA (R6-verified).

typedef short bfrag  __attribute__((ext_vector_type(8)));   // 8 bf16 = 4 VGPRs
typedef float f32x4  __attribute__((ext_vector_type(4)));
typedef float f32x16 __attribute__((ext_vector_type(16)));

static __device__ __forceinline__ short f2bf(float x) {
    unsigned u = __builtin_bit_cast(unsigned, x);
    return (short)((u + 0x8000u) >> 16);       // round-half-up
}
static __device__ __forceinline__ bfrag bzero() {
    bfrag z;
    #pragma unroll
    for (int j = 0; j < 8; ++j) z[j] = 0;
    return z;
}

// ---------------- k_conv (R6-verified) ----------------
__global__ __launch_bounds__(256) void k_conv(
    const float* __restrict__ Wq, const float* __restrict__ Wk,
    const float* __restrict__ Wv, const float* __restrict__ Wout,
    short* __restrict__ Wp, short* __restrict__ Wout_t)
{
    __shared__ short lt[4224];
    const int bid = blockIdx.x, t = threadIdx.x;
    if (bid < 96) {
        const int x = bid >> 5, h = (bid >> 2) & 7, k0 = (bid & 3) * 32;
        const float* W = (x == 0) ? Wq : (x == 1) ? Wk : Wv;
        #pragma unroll 4
        for (int rr = 0; rr < 16; ++rr) {
            const int k = rr * 2 + (t >> 7);
            const int i = t & 127;
            lt[k * 129 + i] = f2bf(W[(k0 + k) * 1024 + i * 8 + h]);
        }
        __syncthreads();
        short* dst = Wp + (x * 8 + h) * 16384;
        #pragma unroll
        for (int pp = 0; pp < 4; ++pp) {
            const int i  = pp * 32 + (t >> 3);
            const int kk = (t & 7) * 4;
            short4 v;
            v.x = lt[(kk + 0) * 129 + i]; v.y = lt[(kk + 1) * 129 + i];
            v.z = lt[(kk + 2) * 129 + i]; v.w = lt[(kk + 3) * 129 + i];
            *(short4*)&dst[i * 128 + k0 + kk] = v;
        }
    } else if (bid < 128) {
        const int b2 = bid - 96;
        const int cq = b2 >> 3, rq = b2 & 7;
        #pragma unroll 4
        for (int ii = 0; ii < 16; ++ii) {
            const int rr = ii * 8 + (t >> 5);
            const int cc = t & 31;
            lt[rr * 33 + cc] = f2bf(Wout[(rq * 128 + rr) * 128 + cq * 32 + cc]);
        }
        __syncthreads();
        #pragma unroll
        for (int ii = 0; ii < 4; ++ii) {
            const int task = ii * 256 + t;
            const int cl = task >> 5, hh = (task >> 2) & 7, mg = task & 3;
            short4 v;
            v.x = lt[(hh + 8 * (mg * 4 + 0)) * 33 + cl];
            v.y = lt[(hh + 8 * (mg * 4 + 1)) * 33 + cl];
            v.z = lt[(hh + 8 * (mg * 4 + 2)) * 33 + cl];
            v.w = lt[(hh + 8 * (mg * 4 + 3)) * 33 + cl];
            *(short4*)&Wout_t[(cq * 32 + cl) * 1024 + hh * 128 + rq * 16 + mg * 4] = v;
        }
    }
}

// ---------------- k_attn ----------------
// LDS (shorts): QT 0..4095 Qt[pl][i][p] | KT 4096..8191 Kt[pl][j][p]
//               VS 8192..12287 Vs[pl][p][j] swizzled (ctx overlay after PV)
#define QT 0
#define KT 4096
#define VS 8192

__global__ __launch_bounds__(256, 4) void k_attn(
    const float* __restrict__ emb,      // [4096][128] fp32
    const short* __restrict__ Wp,       // [3][8][128 i][128 k]
    short* __restrict__ ctx2)           // [4096 out-rows][h*128+i] bf16
{
    __shared__ short lds[12288];        // 24 KB
    const int bid = blockIdx.x;         // 0..1023
    const int pg = bid >> 3, h = bid & 7;
    const int t = threadIdx.x;
    const int w = t >> 6, lane = t & 63;
    const int m16 = lane & 15, quad = lane >> 4, q8 = quad * 8;
    const int l31 = lane & 31, hi = lane >> 5;

    // ===== QKV: (32x128) @ W_h (128x128) x3, 16x16x32 (R6-verified) =====
    {
        bfrag a[2][4];
        #pragma unroll
        for (int tm = 0; tm < 2; ++tm)
            #pragma unroll
            for (int ks = 0; ks < 4; ++ks) {
                const float* er = emb + (size_t)(pg*32 + tm*16 + m16) * 128 + ks*32 + q8;
                const float4 x0 = *(const float4*)er;
                const float4 x1 = *(const float4*)(er + 4);
                bfrag f;
                f[0]=f2bf(x0.x); f[1]=f2bf(x0.y); f[2]=f2bf(x0.z); f[3]=f2bf(x0.w);
                f[4]=f2bf(x1.x); f[5]=f2bf(x1.y); f[6]=f2bf(x1.z); f[7]=f2bf(x1.w);
                a[tm][ks] = f;
            }
        #pragma unroll
        for (int tt = 0; tt < 6; ++tt) {
            const int nt = w * 6 + tt;            // 0..23 = {q,k,v} x 8 i-tiles
            const int x  = nt >> 3;
            const int i0 = (nt & 7) * 16;
            const short* Wb = Wp + ((x*8 + h)*128 + i0 + m16) * 128;
            bfrag bb[4];
            #pragma unroll
            for (int ks = 0; ks < 4; ++ks)
                bb[ks] = *(const bfrag*)&Wb[ks*32 + q8];
            f32x4 c0 = {0.f,0.f,0.f,0.f}, c1 = {0.f,0.f,0.f,0.f};
            #pragma unroll
            for (int ks = 0; ks < 4; ++ks) {
                c0 = __builtin_amdgcn_mfma_f32_16x16x32_bf16(a[0][ks], bb[ks], c0, 0,0,0);
                c1 = __builtin_amdgcn_mfma_f32_16x16x32_bf16(a[1][ks], bb[ks], c1, 0,0,0);
            }
            #pragma unroll
            for (int tm = 0; tm < 2; ++tm) {
                const f32x4 cc = tm ? c1 : c0;
                const int mrow0 = tm*16 + quad*4;
                const int pl = mrow0 >> 3;
                const int p0 = mrow0 & 7;
                const int col = i0 + m16;
                if (x < 2) {                          // Qt/Kt transposed [i][p]
                    short4 v;
                    v.x = f2bf(cc[0]); v.y = f2bf(cc[1]);
                    v.z = f2bf(cc[2]); v.w = f2bf(cc[3]);
                    *(short4*)&lds[(x ? KT : QT) + pl*1024 + col*8 + p0] = v;
                } else {                              // V natural, chunk-swizzled
                    #pragma unroll
                    for (int r = 0; r < 4; ++r) {
                        const int p = p0 + r;
                        const int phys = ((col >> 3) + p + 2*pl) & 15;
                        lds[VS + pl*1024 + p*128 + phys*8 + (col & 7)] = f2bf(cc[r]);
                    }
                }
            }
        }
    }
    __syncthreads();

    // ===== hoist frags: V B-frags (PV), Kt A-frags + Qt B-frags (scores) ====
    bfrag bv[8];                        // B[k=16kt+8hi+jj][n=p=l31]
    #pragma unroll
    for (int kt = 0; kt < 8; ++kt) {
        if (l31 < 8) {
            const int phys = (2*kt + hi + l31 + 2*w) & 15;
            bv[kt] = *(const bfrag*)&lds[VS + w*1024 + l31*128 + phys*8];
        } else if (l31 == 8) {          // ones row -> O[i][8] = rowsum_i
            bfrag o;
            #pragma unroll
            for (int j = 0; j < 8; ++j) o[j] = (short)0x3F80;
            bv[kt] = o;
        } else
            bv[kt] = bzero();
    }
    bfrag ak[4], bq[4];                 // A[m=j=l31+32mt][k=p], B[k=p][n=i=l31+32nt]
    #pragma unroll
    for (int mt = 0; mt < 4; ++mt)
        ak[mt] = (hi == 0) ? *(const bfrag*)&lds[KT + w*1024 + (32*mt + l31)*8] : bzero();
    #pragma unroll
    for (int nt = 0; nt < 4; ++nt)
        bq[nt] = (hi == 0) ? *(const bfrag*)&lds[QT + w*1024 + (32*nt + l31)*8] : bzero();

    // ===== pass 1: instance-norm stats over full map (biased var) =====
    float rs2, nbias;
    {
        float ls = 0.f, lq = 0.f;
        #pragma unroll
        for (int nt = 0; nt < 4; ++nt)
            #pragma unroll
            for (int mt = 0; mt < 4; ++mt) {
                f32x16 c = {};
                c = __builtin_amdgcn_mfma_f32_32x32x16_bf16(ak[mt], bq[nt], c, 0,0,0);
                #pragma unroll
                for (int r = 0; r < 16; ++r) { ls += c[r]; lq = fmaf(c[r], c[r], lq); }
            }
        #pragma unroll
        for (int off = 1; off <= 32; off <<= 1) {
            ls += __shfl_xor(ls, off);
            lq += __shfl_xor(lq, off);
        }
        const float mean = ls * (1.f / 16384.f);
        const float var  = lq * (1.f / 16384.f) - mean * mean;
        rs2   = rsqrtf(var + 1e-5f) * 1.44269504f;       // fold log2(e)
        nbias = -mean * rs2;
    }

    // ===== pass 2: per i-band (32 rows): S^T tiles -> exp -> repack -> PV ===
    #pragma unroll
    for (int nt = 0; nt < 4; ++nt) {
        f32x16 O = {};
        #pragma unroll
        for (int mt = 0; mt < 4; ++mt) {
            f32x16 c = {};
            c = __builtin_amdgcn_mfma_f32_32x32x16_bf16(ak[mt], bq[nt], c, 0,0,0);
            short s[16];
            #pragma unroll
            for (int r = 0; r < 16; ++r)
                s[r] = f2bf(exp2f(fmaf(c[r], rs2, nbias)));
            // repack C-layout -> PV A-frags for kt = 2mt+g (verified mapping):
            //   hi=0: a[jj]=s[8g+jj], a[4+jj]=partner.s[8g+jj]
            //   hi=1: a[jj]=partner.s[8g+4+jj], a[4+jj]=s[8g+4+jj]
            #pragma unroll
            for (int g = 0; g < 2; ++g) {
                bfrag ap;
                #pragma unroll
                for (int jj = 0; jj < 4; ++jj) {
                    const int u = (int)((unsigned short)s[8*g + jj]
                                 | ((unsigned)(unsigned short)s[8*g + 4 + jj] << 16));
                    const int xu = __shfl_xor(u, 32);
                    const short rem_lo = (short)(xu & 0xffff);
                    const short rem_hi = (short)((unsigned)xu >> 16);
                    ap[jj]     = hi ? rem_hi        : s[8*g + jj];
                    ap[4 + jj] = hi ? s[8*g + 4 + jj] : rem_lo;
                }
                O = __builtin_amdgcn_mfma_f32_32x32x16_bf16(ap, bv[2*mt + g], O, 0,0,0);
            }
        }
        // normalize by rowsum (col p=8 of O, same hi-half) and stage ctx
        #pragma unroll
        for (int g = 0; g < 4; ++g) {
            float v[4];
            #pragma unroll
            for (int qd = 0; qd < 4; ++qd) {
                const int r = 4*g + qd;
                const float srow = __shfl(O[r], hi*32 + 8);
                v[qd] = O[r] * __builtin_amdgcn_rcpf(srow);
            }
            if (l31 < 8) {
                const int physc = (4*nt + g + l31) & 15;
                short4 sv;
                sv.x = f2bf(v[0]); sv.y = f2bf(v[1]);
                sv.z = f2bf(v[2]); sv.w = f2bf(v[3]);
                *(short4*)&lds[VS + w*1024 + l31*128 + physc*8 + 4*hi] = sv;
            }
        }
    }

    // ===== ctx -> global ctx2[out_row][h*128+i], coalesced 16B (R6-verified) =
    {
        const int pat = pg*4 + w;
        const int bb = pat >> 5, rem = pat & 31;
        const int dd = rem >> 4, hh = (rem >> 2) & 3, ww = rem & 3;
        #pragma unroll
        for (int it = 0; it < 2; ++it) {
            const int p = it*4 + quad;
            const int cch = m16;
            const int phys = (cch + p) & 15;
            const bfrag v = *(const bfrag*)&lds[VS + w*1024 + p*128 + phys*8];
            const int p1 = p >> 2, p2 = (p >> 1) & 1, p3 = p & 1;
            const int row = bb*256 + ((((dd*2 + p1)*4 + hh)*2 + p2)*4 + ww)*2 + p3;
            *(bfrag*)&ctx2[(size_t)row * 1024 + h*128 + cch*8] = v;
        }
    }
}

// ---------------- k_out (R6-verified) ----------------
__global__ __launch_bounds__(256) void k_out(
    const short* __restrict__ ctx2,    // [4096][1024]
    const short* __restrict__ Wout_t,  // [128 col][1024 k]
    float* __restrict__ out)           // [4096][128]
{
    const int t = threadIdx.x;
    const int w = t >> 6, lane = t & 63;
    const int m16 = lane & 15, quad = lane >> 4, q8 = quad * 8;
    const int row0 = blockIdx.x * 16;

    f32x4 acc0 = {0.f,0.f,0.f,0.f}, acc1 = {0.f,0.f,0.f,0.f};
    const short* ar = ctx2   + (size_t)(row0 + m16) * 1024 + q8;
    const short* b0 = Wout_t + (size_t)((w*2 + 0)*16 + m16) * 1024 + q8;
    const short* b1 = Wout_t + (size_t)((w*2 + 1)*16 + m16) * 1024 + q8;
    #pragma unroll 4
    for (int ks = 0; ks < 32; ++ks) {
        const bfrag a   = *(const bfrag*)&ar[ks*32];
        const bfrag vb0 = *(const bfrag*)&b0[ks*32];
        const bfrag vb1 = *(const bfrag*)&b1[ks*32];
        acc0 = __builtin_amdgcn_mfma_f32_16x16x32_bf16(a, vb0, acc0, 0, 0, 0);
        acc1 = __builtin_amdgcn_mfma_f32_16x16x32_bf16(a, vb1, acc1, 0, 0, 0);
    }
    const int r0 = quad * 4;
    #pragma unroll
    for (int r = 0; r < 4; ++r) {
        out[(size_t)(row0 + r0 + r)*128 + (w*2 + 0)*16 + m16] = acc0[r];
        out[(size_t)(row0 + r0 + r)*128 + (w*2 + 1)*16 + m16] = acc1[r];
    }
}

extern "C" void kernel_launch(void* const* d_in, const int* in_sizes, int n_in,
                              void* d_out, int out_size, void* d_ws, size_t ws_size,
                              hipStream_t stream) {
    const float* emb  = (const float*)d_in[0];   // (512, 8, 128)
    const float* Wq   = (const float*)d_in[1];   // (128, 1024)
    const float* Wk   = (const float*)d_in[2];
    const float* Wv   = (const float*)d_in[3];
    const float* Wout = (const float*)d_in[4];   // (1024, 128)
    float* out = (float*)d_out;                  // 524288 floats

    short* ctx2   = (short*)d_ws;                // 4194304 shorts (8 MB)
    short* Wp     = ctx2 + 4194304;              // 393216
    short* Wout_t = Wp + 393216;                 // 131072

    k_conv<<<128, 256, 0, stream>>>(Wq, Wk, Wv, Wout, Wp, Wout_t);
    k_attn<<<1024, 256, 0, stream>>>(emb, Wp, ctx2);
    k_out<<<256, 256, 0, stream>>>(ctx2, Wout_t, out);
}